// Round 19
// baseline (191.182 us; speedup 1.0000x reference)
//
#include <hip/hip_runtime.h>
#include <hip/hip_bf16.h>

#define B_   32
#define C_   64
#define H_   96
#define W_   96
#define K_   32
#define R_   13
#define HO_  84
#define WO_  84
#define HW_  (H_*W_)      // 9216
#define OHW_ (HO_*WO_)    // 7056
#define CRR_ (C_*R_*R_)   // 10816
#define RR_  (R_*R_)      // 169

#define TILE_ 16          // fallback tile
#define PW_   28          // fallback patch width
// ---- main tile: 12 rows x 32 cols (rows exact: 84 = 7x12) ----
#define TLH_  32          // tile cols (1x32 B-frag)
#define TLV3_ 12          // tile rows (4 waves x 3 one-row frags)
#define PWW_  44          // patch width  = 32+12
#define PHH_  24          // patch height = 12+12
#define NPIX3_ (PHH_*PWW_)  // 1056
#define NEL3_  (2*NPIX3_)   // 2112 16B-elements per pass (= 33 chunks of 64)
#define HB3_   (NPIX3_*16)  // 16896 per ks-half
#define BUF3_  (2*HB3_)     // 33792: single buffer, static alloc
#define NPIX_ (PW_*PW_)   // 784 (fallback)
#define REGB_ (NPIX_*16)  // 12544 (fallback layout)
#define LDS_FB (2*REGB_)  // 25088

// ws layout (new path): xbf4 = [b][pass(4)][pix(9216)][32B]
#define XBF_BYTES  ((size_t)B_*4*HW_*32)         // 37748736
#define UG_BYTES   ((size_t)RR_*4096)            // 692224
#define S_BYTES    ((size_t)B_*HW_*4)            // 1179648
#define INV_BYTES  ((size_t)B_*OHW_*4)           // 903168
#define WS_NEED    (XBF_BYTES + UG_BYTES + S_BYTES + INV_BYTES)

typedef unsigned int u32;
typedef unsigned short u16;
typedef __attribute__((ext_vector_type(16))) float f32x16;
typedef __attribute__((ext_vector_type(4))) u32 u32x4;

static __device__ __forceinline__ u16 f2bf(float v){
    __hip_bfloat16 h = __float2bfloat16(v);  // RNE
    return *reinterpret_cast<u16*>(&h);
}

// D = A*B + D  (32x32x16 bf16)
#define MFMA(acc, a, b) asm("v_mfma_f32_32x32x16_bf16 %0, %1, %2, %0" \
                            : "+v"(acc) : "v"(a), "v"(b))

// async global->LDS DMA, 16B/lane, LDS dest = uniform base + lane*16
static __device__ __forceinline__ void gload_lds16(const void* g, void* l){
    __builtin_amdgcn_global_load_lds(
        (const __attribute__((address_space(1))) unsigned char*)g,
        (__attribute__((address_space(3))) unsigned char*)l, 16, 0, 0);
}

// ---------- device helper: y-norm + bf16 prototype tensor (one k) ----------
// u_g: [pass(4)][jx(13)][i(13)] slices of 1KB; byte = k*32 + (c&15)*2.
// A-frag: lane(kpr,ks) reads 16B at slice + kpr*32 + ks*16.
static __device__ void prep_y_block(const float* __restrict__ y,
                                    unsigned char* __restrict__ u_g,
                                    int k, int tid, float* red){
    const float* yk = y + (size_t)k * CRR_;
    float ss = 0.f;
    for (int idx = tid; idx < CRR_; idx += 256){ float v = yk[idx]; ss += v*v; }
    for (int off = 32; off; off >>= 1) ss += __shfl_down(ss, off);
    if ((tid & 63) == 0) red[tid >> 6] = ss;
    __syncthreads();
    float inv = 1.f / fmaxf(sqrtf(red[0]+red[1]+red[2]+red[3]), 1e-9f);

    int c = tid & 63, grp = tid >> 6;
    int inoff = (k << 5) | ((c & 15) << 1);
    for (int base = 0; base < RR_; base += 4){
        int ij = base + grp;
        if (ij < RR_){
            int i = ij / R_, jx = ij % R_;
            float v = yk[c*RR_ + ij] * inv;
            size_t slice = ((size_t)(c >> 4) * RR_ + jx*R_ + i) << 10;
            *(u16*)(u_g + slice + inoff) = f2bf(v);
        }
    }
}

// k1 standalone (fallback path)
__global__ void k_prep_y(const float* __restrict__ y, unsigned char* __restrict__ u_g){
    __shared__ float red[4];
    prep_y_block(y, u_g, blockIdx.x, threadIdx.x, red);
}

// ------- merged k1+k2: blocks 0..31 do y-prep; rest do sqcvt ---------------
__global__ void k_prep(const float* __restrict__ x, const float* __restrict__ y,
                       float* __restrict__ s, unsigned char* __restrict__ xbf,
                       unsigned char* __restrict__ u_g){
    __shared__ float red[4];
    int bb = blockIdx.x;
    if (bb < K_){ prep_y_block(y, u_g, bb, threadIdx.x, red); return; }
    int idx = (bb - K_)*256 + threadIdx.x;            // < 294912 exact
    int b = idx / HW_, r = idx % HW_;
    const float* xb = x + (size_t)b * C_ * HW_ + r;
    float acc = 0.f;
    #pragma unroll
    for (int q = 0; q < 4; ++q){
        int c0 = q*16;
        float a0 = xb[(size_t)(c0+0)*HW_],  a1 = xb[(size_t)(c0+1)*HW_];
        float a2 = xb[(size_t)(c0+2)*HW_],  a3 = xb[(size_t)(c0+3)*HW_];
        float a4 = xb[(size_t)(c0+4)*HW_],  a5 = xb[(size_t)(c0+5)*HW_];
        float a6 = xb[(size_t)(c0+6)*HW_],  a7 = xb[(size_t)(c0+7)*HW_];
        float a8 = xb[(size_t)(c0+8)*HW_],  a9 = xb[(size_t)(c0+9)*HW_];
        float aa = xb[(size_t)(c0+10)*HW_], ab = xb[(size_t)(c0+11)*HW_];
        float ac = xb[(size_t)(c0+12)*HW_], ad = xb[(size_t)(c0+13)*HW_];
        float ae = xb[(size_t)(c0+14)*HW_], af = xb[(size_t)(c0+15)*HW_];
        acc += a0*a0+a1*a1+a2*a2+a3*a3+a4*a4+a5*a5+a6*a6+a7*a7
             + a8*a8+a9*a9+aa*aa+ab*ab+ac*ac+ad*ad+ae*ae+af*af;
        u32x4 q0 = { f2bf(a0)|((u32)f2bf(a1)<<16), f2bf(a2)|((u32)f2bf(a3)<<16),
                     f2bf(a4)|((u32)f2bf(a5)<<16), f2bf(a6)|((u32)f2bf(a7)<<16) };
        u32x4 q1 = { f2bf(a8)|((u32)f2bf(a9)<<16), f2bf(aa)|((u32)f2bf(ab)<<16),
                     f2bf(ac)|((u32)f2bf(ad)<<16), f2bf(ae)|((u32)f2bf(af)<<16) };
        unsigned char* ob = xbf + ((size_t)(b*4 + q)*HW_ + r)*32;
        *(u32x4*)(ob)      = q0;
        *(u32x4*)(ob + 16) = q1;
    }
    s[idx] = acc;
}

// plain k2 for fallback path
__global__ void k_sq(const float* __restrict__ x, float* __restrict__ s){
    int idx = blockIdx.x*256 + threadIdx.x;
    int b = idx / HW_, r = idx % HW_;
    const float* xb = x + (size_t)b * C_ * HW_;
    float acc = 0.f;
    #pragma unroll
    for (int c = 0; c < C_; ++c){ float v = xb[(size_t)c*HW_ + r]; acc += v*v; }
    s[idx] = acc;
}

// ---------------- k3: inv_xn = 1/max(sqrt(13x13 box sum), eps) -------------
__global__ void k_inv(const float* __restrict__ s, float* __restrict__ inv_xn){
    int idx = blockIdx.x*256 + threadIdx.x;           // < 225792 exact
    int b = idx / OHW_, r = idx % OHW_;
    int oh = r / WO_, ow = r % WO_;
    const float* sb = s + (size_t)b*HW_ + oh*W_ + ow;
    float acc = 0.f;
    for (int i = 0; i < R_; ++i){
        #pragma unroll
        for (int j = 0; j < R_; ++j) acc += sb[i*W_ + j];
    }
    inv_xn[idx] = 1.f / fmaxf(sqrtf(acc), 1e-9f);
}

// ---------------- k_main: fused cosine-similarity conv ---------------------
// 12x32 tile (1-row x 32-col B-frags), rows exact (84 = 7x12), 3-row rolling
// window, i<12 refill guard. R18: __launch_bounds__(256,4) — R17 proved the
// ~2-block/CU residency cap isn't LDS accounting; R13 showed occupancy DID
// rise with bound=4 (despite its spill). This kernel is light (72 VGPR under
// bound-3; bound-4 cap=128 >= natural use) -> request 4 blocks/CU, no spill.
__launch_bounds__(256, 4)
__global__ void k_main(const unsigned char* __restrict__ xbf,
                       const unsigned char* __restrict__ u_g,
                       const float* __restrict__ inv_xn, float* __restrict__ out){
    __shared__ unsigned char lds[BUF3_];   // static, exact size

    int bb0 = blockIdx.x;
    int bb  = (bb0 & 7) * 84 + (bb0 >> 3);   // XCD-chunked swizzle (672 = 8*84)
    int b  = bb / 21;
    int tt = bb % 21;
    int oy = (tt / 3) * TLV3_;               // 0..72, rows exact
    int ox = (tt % 3) * TLH_;                // 0,32,64 (64-tile: cols >=84 masked)

    int tid  = threadIdx.x;
    int lane = tid & 63;
    int wv   = tid >> 6;        // 0..3
    int ks   = lane >> 5;       // k-half of MFMA operands
    int nn   = lane & 31;       // B-frag col within tile / D col
    int kpr  = lane & 31;       // prototype row for A-frag

    const unsigned char* xq = xbf + (size_t)b*4*HW_*32;   // image base (pass-major)
    int aoff = (kpr << 5) + (ks << 4);      // A lane offset within 1KB slice
    int pb3  = (3*wv)*PWW_ + nn;            // frag f at tap(i,jx): pb3 + (i+f)*PWW_ + jx

    // staging: 36 padded chunks of 64 elements (16B each), 9 per wave.
    // flat element e = h*NPIX3 + p -> LDS byte e*16 (uniform base + lane*16
    // holds for ALL chunks since HB3 = NPIX3*16). Chunks 33-35 remap to 32
    // (duplicate writes of identical data: benign).
    int goff[9], loff[9];
    #pragma unroll
    for (int j = 0; j < 9; ++j){
        int cb = wv + 4*j;
        int cs = cb*64; if (cs > NEL3_-64) cs = NEL3_-64;   // 2048 cap
        int e = cs + lane;
        int h = (e >= NPIX3_);
        int p = e - (h ? NPIX3_ : 0);
        int py = p / PWW_, px = p % PWW_;
        int gy = oy + py;                             // <= 72+23 = 95: in-bounds
        int gx = ox + px; if (gx > W_-1) gx = W_-1;   // clamp feeds only invalid cols
        goff[j] = ((gy*W_ + gx) << 5) + h*16;         // pass-major pixel stride 32B
        loff[j] = cs << 4;                            // uniform chunk base
    }

#define STAGE(q) {                                                           \
        const unsigned char* src = xq + (size_t)(q)*HW_*32;                  \
        _Pragma("unroll")                                                    \
        for (int j = 0; j < 9; ++j)                                          \
            gload_lds16(src + goff[j], lds + loff[j]);                       \
    }

    f32x16 acc0 = {}, acc1 = {}, acc2 = {};
    STAGE(0);
    __syncthreads();            // vmcnt drained at barrier -> pass-0 visible

    for (int pass = 0; pass < 4; ++pass){
        const unsigned char* xh = lds + ks*HB3_;
        const unsigned char* ug = u_g + ((size_t)pass*RR_ << 10);

        u32x4 A0 = *(const u32x4*)(ug              + aoff);
        u32x4 A1 = *(const u32x4*)(ug + (1 << 10)  + aoff);
        u32x4 A2 = *(const u32x4*)(ug + (2 << 10)  + aoff);
        u32x4 A3 = *(const u32x4*)(ug + (3 << 10)  + aoff);

        // initial 3-row window for jx=0
        const unsigned char* col0 = xh + pb3*16;
        u32x4 w0 = *(const u32x4*)(col0);
        u32x4 w1 = *(const u32x4*)(col0 +   PWW_*16);
        u32x4 w2 = *(const u32x4*)(col0 + 2*PWW_*16);

        int t = 0;
        for (int jx = 0; jx < R_; ++jx){
            const unsigned char* col  = xh + (pb3 + jx)*16;
            const unsigned char* ncol = col + 16;       // next column (jx+1)
            u32x4 e0, e1, e2;
            #pragma unroll
            for (int i = 0; i < R_; ++i, ++t){
                int tn = t + 4; if (tn > RR_-1) tn = RR_-1;
                u32x4 An = *(const u32x4*)(ug + ((size_t)tn << 10) + aoff);
                u32x4 wn = w2;
                if (i < 12) wn = *(const u32x4*)(col + (i+3)*PWW_*16);
                // prefetch next-jx window rows 0..2 during tail iters
                if (i == 9)  e0 = *(const u32x4*)(ncol);
                if (i == 10) e1 = *(const u32x4*)(ncol +   PWW_*16);
                if (i == 11) e2 = *(const u32x4*)(ncol + 2*PWW_*16);
                __builtin_amdgcn_s_setprio(1);
                MFMA(acc0, A0, w0);     // frag0 (row +0): B = patch row i
                MFMA(acc1, A0, w1);     // frag1 (row +1): B = patch row i+1
                MFMA(acc2, A0, w2);     // frag2 (row +2): B = patch row i+2
                __builtin_amdgcn_s_setprio(0);
                A0 = A1; A1 = A2; A2 = A3; A3 = An;
                w0 = w1; w1 = w2; w2 = wn;
            }
            w0 = e0; w1 = e1; w2 = e2;  // last jx: dead
        }

        if (pass < 3){
            __syncthreads();    // all reads of this pass complete
            STAGE(pass+1);      // issue DMA into the (single) buffer
            __syncthreads();    // vmcnt drained -> next pass visible
        }
    }

    // ---- epilogue: relu(num) * 1/||x_win||; D: col=lane&31,
    // row = (r&3) + 8*(r>>2) + 4*(lane>>5) ----
    int ow = ox + nn;
    bool valid = (ow < WO_);    // rows always valid (84 = 7x12)
#define EPI(ACC, F) {                                                        \
        int oh = oy + 3*wv + (F);                                            \
        float inv = 0.f;                                                     \
        if (valid) inv = inv_xn[(size_t)b*OHW_ + oh*WO_ + ow];               \
        float* ob = out + (size_t)b*K_*OHW_ + oh*WO_ + ow;                   \
        _Pragma("unroll")                                                    \
        for (int r = 0; r < 16; ++r){                                        \
            int kp = (r & 3) + 8*(r >> 2) + 4*ks;                            \
            if (valid) ob[(size_t)kp*OHW_] = fmaxf(ACC[r], 0.f) * inv;       \
        }                                                                    \
    }
    EPI(acc0, 0); EPI(acc1, 1); EPI(acc2, 2);
#undef EPI
}

// ---------------- fallback k_main (R5, ds_write staging) -------------------
__launch_bounds__(256, 4)
__global__ void k_main_fb(const float* __restrict__ x, const unsigned char* __restrict__ u_g,
                          const float* __restrict__ inv_xn, float* __restrict__ out){
    extern __shared__ unsigned char lds[];
    int bb = blockIdx.x;
    int b  = bb / 36;
    int tt = bb % 36;
    int oy = (tt / 6) * TILE_;
    int ox = (tt % 6) * TILE_;
    int tid  = threadIdx.x;
    int lane = tid & 63;
    int wv   = tid >> 6;
    int ks   = lane >> 5;
    int rb   = (lane >> 4) & 1;
    int cx   = lane & 15;
    int kpr  = lane & 31;
    const float* xb = x + (size_t)b * C_ * HW_;
    int aoff = (kpr << 5) + (ks << 4);
    int pb   = (4*wv + rb) * PW_ + cx;
    f32x16 acc0 = {}, acc1 = {};
    for (int pass = 0; pass < 4; ++pass){
        if (pass) __syncthreads();
        int cbase = pass << 4;
        for (int p = tid; p < NPIX_; p += 256){
            int py = p / PW_, px = p % PW_;
            int gy = oy + py; if (gy > H_-1) gy = H_-1;
            int gx = ox + px; if (gx > W_-1) gx = W_-1;
            const float* src = xb + (size_t)cbase*HW_ + gy*W_ + gx;
            u32 w0 = f2bf(src[0*HW_])  | ((u32)f2bf(src[1*HW_])  << 16);
            u32 w1 = f2bf(src[2*HW_])  | ((u32)f2bf(src[3*HW_])  << 16);
            u32 w2 = f2bf(src[4*HW_])  | ((u32)f2bf(src[5*HW_])  << 16);
            u32 w3 = f2bf(src[6*HW_])  | ((u32)f2bf(src[7*HW_])  << 16);
            u32x4 q0 = {w0, w1, w2, w3};
            u32 v0 = f2bf(src[8*HW_])  | ((u32)f2bf(src[9*HW_])  << 16);
            u32 v1 = f2bf(src[10*HW_]) | ((u32)f2bf(src[11*HW_]) << 16);
            u32 v2 = f2bf(src[12*HW_]) | ((u32)f2bf(src[13*HW_]) << 16);
            u32 v3 = f2bf(src[14*HW_]) | ((u32)f2bf(src[15*HW_]) << 16);
            u32x4 q1 = {v0, v1, v2, v3};
            *(u32x4*)(lds +         p*16) = q0;
            *(u32x4*)(lds + REGB_ + p*16) = q1;
        }
        __syncthreads();
        const unsigned char* xh = lds + ks*REGB_;
        const unsigned char* ug = u_g + ((size_t)pass*RR_ << 10);
        u32x4 A0 = *(const u32x4*)(ug              + aoff);
        u32x4 A1 = *(const u32x4*)(ug + (1 << 10)  + aoff);
        u32x4 A2 = *(const u32x4*)(ug + (2 << 10)  + aoff);
        u32x4 A3 = *(const u32x4*)(ug + (3 << 10)  + aoff);
        int t = 0;
        for (int jx = 0; jx < R_; ++jx){
            const unsigned char* col = xh + (pb + jx)*16;
            u32x4 d0 = *(const u32x4*)(col);
            u32x4 d1 = *(const u32x4*)(col +   PW_*16);
            u32x4 d2 = *(const u32x4*)(col + 2*PW_*16);
            u32x4 d3 = *(const u32x4*)(col + 3*PW_*16);
            u32x4 d4 = *(const u32x4*)(col + 4*PW_*16);
            #pragma unroll
            for (int i = 0; i < R_; ++i, ++t){
                int tn = t + 4; if (tn > RR_-1) tn = RR_-1;
                u32x4 An = *(const u32x4*)(ug + ((size_t)tn << 10) + aoff);
                u32x4 dn = d4;
                if (i < 10) dn = *(const u32x4*)(col + (i+5)*PW_*16);
                MFMA(acc0, A0, d0);
                MFMA(acc1, A0, d2);
                A0 = A1; A1 = A2; A2 = A3; A3 = An;
                d0 = d1; d1 = d2; d2 = d3; d3 = d4; d4 = dn;
            }
        }
    }
    int ow = ox + cx;
#define EPI(ACC, F) {                                                        \
        int oh = oy + 4*wv + rb + 2*(F);                                     \
        bool valid = (oh < HO_) && (ow < WO_);                               \
        float inv = 0.f;                                                     \
        if (valid) inv = inv_xn[(size_t)b*OHW_ + oh*WO_ + ow];               \
        float* ob = out + (size_t)b*K_*OHW_ + oh*WO_ + ow;                   \
        _Pragma("unroll")                                                    \
        for (int r = 0; r < 16; ++r){                                        \
            int kp = (r & 3) + 8*(r >> 2) + 4*ks;                            \
            if (valid) ob[(size_t)kp*OHW_] = fmaxf(ACC[r], 0.f) * inv;       \
        }                                                                    \
    }
    EPI(acc0, 0); EPI(acc1, 1);
#undef EPI
}

extern "C" void kernel_launch(void* const* d_in, const int* in_sizes, int n_in,
                              void* d_out, int out_size, void* d_ws, size_t ws_size,
                              hipStream_t stream) {
    const float* x = (const float*)d_in[0];
    const float* y = (const float*)d_in[1];
    float* out = (float*)d_out;
    unsigned char* ws = (unsigned char*)d_ws;

    if (ws_size >= WS_NEED){
        unsigned char* xbf   = ws;
        unsigned char* u_g   = ws + XBF_BYTES;
        float*         s     = (float*)(ws + XBF_BYTES + UG_BYTES);
        float*         invxn = (float*)(ws + XBF_BYTES + UG_BYTES + S_BYTES);

        k_prep<<<K_ + (B_*HW_)/256, 256, 0, stream>>>(x, y, s, xbf, u_g);
        k_inv<<<(B_*OHW_)/256, 256, 0, stream>>>(s, invxn);
        k_main<<<B_*21, 256, 0, stream>>>(xbf, u_g, invxn, out);
    } else {
        unsigned char* u_g   = ws;
        float*         s     = (float*)(ws + UG_BYTES);
        float*         invxn = (float*)(ws + UG_BYTES + S_BYTES);

        k_prep_y<<<K_, 256, 0, stream>>>(y, u_g);
        k_sq<<<(B_*HW_)/256, 256, 0, stream>>>(x, s);
        k_inv<<<(B_*OHW_)/256, 256, 0, stream>>>(s, invxn);
        k_main_fb<<<B_*36, 256, LDS_FB, stream>>>(x, u_g, invxn, out);
    }
}

// Round 20
// 191.090 us; speedup vs baseline: 1.0005x; 1.0005x over previous
//
#include <hip/hip_runtime.h>
#include <hip/hip_bf16.h>

#define B_   32
#define C_   64
#define H_   96
#define W_   96
#define K_   32
#define R_   13
#define HO_  84
#define WO_  84
#define HW_  (H_*W_)      // 9216
#define OHW_ (HO_*WO_)    // 7056
#define CRR_ (C_*R_*R_)   // 10816
#define RR_  (R_*R_)      // 169

#define TILE_ 16          // fallback tile
#define PW_   28          // fallback patch width
// ---- main tile: 12 rows x 32 cols (rows exact: 84 = 7x12) ----
#define TLH_  32          // tile cols (1x32 B-frag)
#define TLV3_ 12          // tile rows (4 waves x 3 one-row frags)
#define PWW_  44          // patch width  = 32+12
#define PHH_  24          // patch height = 12+12
#define NPIX3_ (PHH_*PWW_)  // 1056
#define NEL3_  (2*NPIX3_)   // 2112 16B-elements per pass (= 33 chunks of 64)
#define HB3_   (NPIX3_*16)  // 16896 per ks-half
#define BUF3_  (2*HB3_)     // 33792 per pass-buffer
#define NPIX_ (PW_*PW_)   // 784 (fallback)
#define REGB_ (NPIX_*16)  // 12544 (fallback layout)
#define LDS_FB (2*REGB_)  // 25088

// ws layout (new path): xbf4 = [b][pass(4)][pix(9216)][32B]
#define XBF_BYTES  ((size_t)B_*4*HW_*32)         // 37748736
#define UG_BYTES   ((size_t)RR_*4096)            // 692224
#define S_BYTES    ((size_t)B_*HW_*4)            // 1179648
#define INV_BYTES  ((size_t)B_*OHW_*4)           // 903168
#define WS_NEED    (XBF_BYTES + UG_BYTES + S_BYTES + INV_BYTES)

typedef unsigned int u32;
typedef unsigned short u16;
typedef __attribute__((ext_vector_type(16))) float f32x16;
typedef __attribute__((ext_vector_type(4))) u32 u32x4;

static __device__ __forceinline__ u16 f2bf(float v){
    __hip_bfloat16 h = __float2bfloat16(v);  // RNE
    return *reinterpret_cast<u16*>(&h);
}

// D = A*B + D  (32x32x16 bf16)
#define MFMA(acc, a, b) asm("v_mfma_f32_32x32x16_bf16 %0, %1, %2, %0" \
                            : "+v"(acc) : "v"(a), "v"(b))

// async global->LDS DMA, 16B/lane, LDS dest = uniform base + lane*16
static __device__ __forceinline__ void gload_lds16(const void* g, void* l){
    __builtin_amdgcn_global_load_lds(
        (const __attribute__((address_space(1))) unsigned char*)g,
        (__attribute__((address_space(3))) unsigned char*)l, 16, 0, 0);
}

// ---------- device helper: y-norm + bf16 prototype tensor (one k) ----------
// u_g: [pass(4)][jx(13)][i(13)] slices of 1KB; byte = k*32 + (c&15)*2.
// A-frag: lane(kpr,ks) reads 16B at slice + kpr*32 + ks*16.
static __device__ void prep_y_block(const float* __restrict__ y,
                                    unsigned char* __restrict__ u_g,
                                    int k, int tid, float* red){
    const float* yk = y + (size_t)k * CRR_;
    float ss = 0.f;
    for (int idx = tid; idx < CRR_; idx += 256){ float v = yk[idx]; ss += v*v; }
    for (int off = 32; off; off >>= 1) ss += __shfl_down(ss, off);
    if ((tid & 63) == 0) red[tid >> 6] = ss;
    __syncthreads();
    float inv = 1.f / fmaxf(sqrtf(red[0]+red[1]+red[2]+red[3]), 1e-9f);

    int c = tid & 63, grp = tid >> 6;
    int inoff = (k << 5) | ((c & 15) << 1);
    for (int base = 0; base < RR_; base += 4){
        int ij = base + grp;
        if (ij < RR_){
            int i = ij / R_, jx = ij % R_;
            float v = yk[c*RR_ + ij] * inv;
            size_t slice = ((size_t)(c >> 4) * RR_ + jx*R_ + i) << 10;
            *(u16*)(u_g + slice + inoff) = f2bf(v);
        }
    }
}

// k1 standalone (fallback path)
__global__ void k_prep_y(const float* __restrict__ y, unsigned char* __restrict__ u_g){
    __shared__ float red[4];
    prep_y_block(y, u_g, blockIdx.x, threadIdx.x, red);
}

// ------- merged k1+k2: blocks 0..31 do y-prep; rest do sqcvt ---------------
__global__ void k_prep(const float* __restrict__ x, const float* __restrict__ y,
                       float* __restrict__ s, unsigned char* __restrict__ xbf,
                       unsigned char* __restrict__ u_g){
    __shared__ float red[4];
    int bb = blockIdx.x;
    if (bb < K_){ prep_y_block(y, u_g, bb, threadIdx.x, red); return; }
    int idx = (bb - K_)*256 + threadIdx.x;            // < 294912 exact
    int b = idx / HW_, r = idx % HW_;
    const float* xb = x + (size_t)b * C_ * HW_ + r;
    float acc = 0.f;
    #pragma unroll
    for (int q = 0; q < 4; ++q){
        int c0 = q*16;
        float a0 = xb[(size_t)(c0+0)*HW_],  a1 = xb[(size_t)(c0+1)*HW_];
        float a2 = xb[(size_t)(c0+2)*HW_],  a3 = xb[(size_t)(c0+3)*HW_];
        float a4 = xb[(size_t)(c0+4)*HW_],  a5 = xb[(size_t)(c0+5)*HW_];
        float a6 = xb[(size_t)(c0+6)*HW_],  a7 = xb[(size_t)(c0+7)*HW_];
        float a8 = xb[(size_t)(c0+8)*HW_],  a9 = xb[(size_t)(c0+9)*HW_];
        float aa = xb[(size_t)(c0+10)*HW_], ab = xb[(size_t)(c0+11)*HW_];
        float ac = xb[(size_t)(c0+12)*HW_], ad = xb[(size_t)(c0+13)*HW_];
        float ae = xb[(size_t)(c0+14)*HW_], af = xb[(size_t)(c0+15)*HW_];
        acc += a0*a0+a1*a1+a2*a2+a3*a3+a4*a4+a5*a5+a6*a6+a7*a7
             + a8*a8+a9*a9+aa*aa+ab*ab+ac*ac+ad*ad+ae*ae+af*af;
        u32x4 q0 = { f2bf(a0)|((u32)f2bf(a1)<<16), f2bf(a2)|((u32)f2bf(a3)<<16),
                     f2bf(a4)|((u32)f2bf(a5)<<16), f2bf(a6)|((u32)f2bf(a7)<<16) };
        u32x4 q1 = { f2bf(a8)|((u32)f2bf(a9)<<16), f2bf(aa)|((u32)f2bf(ab)<<16),
                     f2bf(ac)|((u32)f2bf(ad)<<16), f2bf(ae)|((u32)f2bf(af)<<16) };
        unsigned char* ob = xbf + ((size_t)(b*4 + q)*HW_ + r)*32;
        *(u32x4*)(ob)      = q0;
        *(u32x4*)(ob + 16) = q1;
    }
    s[idx] = acc;
}

// plain k2 for fallback path
__global__ void k_sq(const float* __restrict__ x, float* __restrict__ s){
    int idx = blockIdx.x*256 + threadIdx.x;
    int b = idx / HW_, r = idx % HW_;
    const float* xb = x + (size_t)b * C_ * HW_;
    float acc = 0.f;
    #pragma unroll
    for (int c = 0; c < C_; ++c){ float v = xb[(size_t)c*HW_ + r]; acc += v*v; }
    s[idx] = acc;
}

// ---------------- k3: inv_xn = 1/max(sqrt(13x13 box sum), eps) -------------
__global__ void k_inv(const float* __restrict__ s, float* __restrict__ inv_xn){
    int idx = blockIdx.x*256 + threadIdx.x;           // < 225792 exact
    int b = idx / OHW_, r = idx % OHW_;
    int oh = r / WO_, ow = r % WO_;
    const float* sb = s + (size_t)b*HW_ + oh*W_ + ow;
    float acc = 0.f;
    for (int i = 0; i < R_; ++i){
        #pragma unroll
        for (int j = 0; j < R_; ++j) acc += sb[i*W_ + j];
    }
    inv_xn[idx] = 1.f / fmaxf(sqrtf(acc), 1e-9f);
}

// ---------------- k_main: fused cosine-similarity conv ---------------------
// 12x32 tile, 3-row rolling window, i<12 refill (R16). R19 micro-trims at
// the structural 2-block/CU residency cap (R17/R18 decisive):
//  (1) dbuf LDS (2x33792 static; free at the cap) -> 1 barrier/pass, the
//      per-pass serial DMA drain hides under the previous pass's compute.
//  (2) A-prefetch clamp removed: read ug+(t+4)<<10 unconditionally; <=4KB
//      overrun lands in the s buffer (valid memory; values provably dead).
__launch_bounds__(256, 2)
__global__ void k_main(const unsigned char* __restrict__ xbf,
                       const unsigned char* __restrict__ u_g,
                       const float* __restrict__ inv_xn, float* __restrict__ out){
    __shared__ unsigned char lds[2*BUF3_];   // static dbuf, 67584 B

    int bb0 = blockIdx.x;
    int bb  = (bb0 & 7) * 84 + (bb0 >> 3);   // XCD-chunked swizzle (672 = 8*84)
    int b  = bb / 21;
    int tt = bb % 21;
    int oy = (tt / 3) * TLV3_;               // 0..72, rows exact
    int ox = (tt % 3) * TLH_;                // 0,32,64 (cols >=84 masked)

    int tid  = threadIdx.x;
    int lane = tid & 63;
    int wv   = tid >> 6;        // 0..3
    int ks   = lane >> 5;       // k-half of MFMA operands
    int nn   = lane & 31;       // B-frag col within tile / D col
    int kpr  = lane & 31;       // prototype row for A-frag

    const unsigned char* xq = xbf + (size_t)b*4*HW_*32;   // image base (pass-major)
    int aoff = (kpr << 5) + (ks << 4);      // A lane offset within 1KB slice
    int pb3  = (3*wv)*PWW_ + nn;            // frag f at tap(i,jx): pb3 + (i+f)*PWW_ + jx

    // staging: 36 padded chunks of 64 elements (16B each), 9 per wave.
    int goff[9], loff[9];
    #pragma unroll
    for (int j = 0; j < 9; ++j){
        int cb = wv + 4*j;
        int cs = cb*64; if (cs > NEL3_-64) cs = NEL3_-64;   // 2048 cap
        int e = cs + lane;
        int h = (e >= NPIX3_);
        int p = e - (h ? NPIX3_ : 0);
        int py = p / PWW_, px = p % PWW_;
        int gy = oy + py;                             // <= 95: in-bounds
        int gx = ox + px; if (gx > W_-1) gx = W_-1;   // clamp feeds only invalid cols
        goff[j] = ((gy*W_ + gx) << 5) + h*16;         // pass-major pixel stride 32B
        loff[j] = cs << 4;                            // uniform chunk base
    }

#define STAGE(bufsel, q) {                                                   \
        const unsigned char* src = xq + (size_t)(q)*HW_*32;                  \
        unsigned char* dst = lds + (bufsel)*BUF3_;                           \
        _Pragma("unroll")                                                    \
        for (int j = 0; j < 9; ++j)                                          \
            gload_lds16(src + goff[j], dst + loff[j]);                       \
    }

    f32x16 acc0 = {}, acc1 = {}, acc2 = {};
    STAGE(0, 0);

    for (int pass = 0; pass < 4; ++pass){
        __syncthreads();        // drains vmcnt -> buf[pass&1] staged & visible
        if (pass < 3) STAGE((pass+1)&1, pass+1);   // async, hidden under compute

        const unsigned char* xh = lds + (pass&1)*BUF3_ + ks*HB3_;
        const unsigned char* ug = u_g + ((size_t)pass*RR_ << 10);

        u32x4 A0 = *(const u32x4*)(ug              + aoff);
        u32x4 A1 = *(const u32x4*)(ug + (1 << 10)  + aoff);
        u32x4 A2 = *(const u32x4*)(ug + (2 << 10)  + aoff);
        u32x4 A3 = *(const u32x4*)(ug + (3 << 10)  + aoff);

        // initial 3-row window for jx=0
        const unsigned char* col0 = xh + pb3*16;
        u32x4 w0 = *(const u32x4*)(col0);
        u32x4 w1 = *(const u32x4*)(col0 +   PWW_*16);
        u32x4 w2 = *(const u32x4*)(col0 + 2*PWW_*16);

        int t = 0;
        for (int jx = 0; jx < R_; ++jx){
            const unsigned char* col  = xh + (pb3 + jx)*16;
            const unsigned char* ncol = col + 16;       // next column (jx+1)
            u32x4 e0, e1, e2;
            #pragma unroll
            for (int i = 0; i < R_; ++i, ++t){
                // unclamped A-prefetch: overrun (<=4 slices) reads into the s
                // buffer; those window entries are dead at pass end.
                u32x4 An = *(const u32x4*)(ug + ((size_t)(t+4) << 10) + aoff);
                u32x4 wn = w2;
                if (i < 12) wn = *(const u32x4*)(col + (i+3)*PWW_*16);
                // prefetch next-jx window rows 0..2 during tail iters
                if (i == 9)  e0 = *(const u32x4*)(ncol);
                if (i == 10) e1 = *(const u32x4*)(ncol +   PWW_*16);
                if (i == 11) e2 = *(const u32x4*)(ncol + 2*PWW_*16);
                __builtin_amdgcn_s_setprio(1);
                MFMA(acc0, A0, w0);     // frag0 (row +0): B = patch row i
                MFMA(acc1, A0, w1);     // frag1 (row +1): B = patch row i+1
                MFMA(acc2, A0, w2);     // frag2 (row +2): B = patch row i+2
                __builtin_amdgcn_s_setprio(0);
                A0 = A1; A1 = A2; A2 = A3; A3 = An;
                w0 = w1; w1 = w2; w2 = wn;
            }
            w0 = e0; w1 = e1; w2 = e2;  // last jx: dead
        }
    }

    // ---- epilogue: relu(num) * 1/||x_win||; D: col=lane&31,
    // row = (r&3) + 8*(r>>2) + 4*(lane>>5) ----
    int ow = ox + nn;
    bool valid = (ow < WO_);    // rows always valid (84 = 7x12)
#define EPI(ACC, F) {                                                        \
        int oh = oy + 3*wv + (F);                                            \
        float inv = 0.f;                                                     \
        if (valid) inv = inv_xn[(size_t)b*OHW_ + oh*WO_ + ow];               \
        float* ob = out + (size_t)b*K_*OHW_ + oh*WO_ + ow;                   \
        _Pragma("unroll")                                                    \
        for (int r = 0; r < 16; ++r){                                        \
            int kp = (r & 3) + 8*(r >> 2) + 4*ks;                            \
            if (valid) ob[(size_t)kp*OHW_] = fmaxf(ACC[r], 0.f) * inv;       \
        }                                                                    \
    }
    EPI(acc0, 0); EPI(acc1, 1); EPI(acc2, 2);
#undef EPI
}

// ---------------- fallback k_main (R5, ds_write staging) -------------------
__launch_bounds__(256, 4)
__global__ void k_main_fb(const float* __restrict__ x, const unsigned char* __restrict__ u_g,
                          const float* __restrict__ inv_xn, float* __restrict__ out){
    extern __shared__ unsigned char lds[];
    int bb = blockIdx.x;
    int b  = bb / 36;
    int tt = bb % 36;
    int oy = (tt / 6) * TILE_;
    int ox = (tt % 6) * TILE_;
    int tid  = threadIdx.x;
    int lane = tid & 63;
    int wv   = tid >> 6;
    int ks   = lane >> 5;
    int rb   = (lane >> 4) & 1;
    int cx   = lane & 15;
    int kpr  = lane & 31;
    const float* xb = x + (size_t)b * C_ * HW_;
    int aoff = (kpr << 5) + (ks << 4);
    int pb   = (4*wv + rb) * PW_ + cx;
    f32x16 acc0 = {}, acc1 = {};
    for (int pass = 0; pass < 4; ++pass){
        if (pass) __syncthreads();
        int cbase = pass << 4;
        for (int p = tid; p < NPIX_; p += 256){
            int py = p / PW_, px = p % PW_;
            int gy = oy + py; if (gy > H_-1) gy = H_-1;
            int gx = ox + px; if (gx > W_-1) gx = W_-1;
            const float* src = xb + (size_t)cbase*HW_ + gy*W_ + gx;
            u32 w0 = f2bf(src[0*HW_])  | ((u32)f2bf(src[1*HW_])  << 16);
            u32 w1 = f2bf(src[2*HW_])  | ((u32)f2bf(src[3*HW_])  << 16);
            u32 w2 = f2bf(src[4*HW_])  | ((u32)f2bf(src[5*HW_])  << 16);
            u32 w3 = f2bf(src[6*HW_])  | ((u32)f2bf(src[7*HW_])  << 16);
            u32x4 q0 = {w0, w1, w2, w3};
            u32 v0 = f2bf(src[8*HW_])  | ((u32)f2bf(src[9*HW_])  << 16);
            u32 v1 = f2bf(src[10*HW_]) | ((u32)f2bf(src[11*HW_]) << 16);
            u32 v2 = f2bf(src[12*HW_]) | ((u32)f2bf(src[13*HW_]) << 16);
            u32 v3 = f2bf(src[14*HW_]) | ((u32)f2bf(src[15*HW_]) << 16);
            u32x4 q1 = {v0, v1, v2, v3};
            *(u32x4*)(lds +         p*16) = q0;
            *(u32x4*)(lds + REGB_ + p*16) = q1;
        }
        __syncthreads();
        const unsigned char* xh = lds + ks*REGB_;
        const unsigned char* ug = u_g + ((size_t)pass*RR_ << 10);
        u32x4 A0 = *(const u32x4*)(ug              + aoff);
        u32x4 A1 = *(const u32x4*)(ug + (1 << 10)  + aoff);
        u32x4 A2 = *(const u32x4*)(ug + (2 << 10)  + aoff);
        u32x4 A3 = *(const u32x4*)(ug + (3 << 10)  + aoff);
        int t = 0;
        for (int jx = 0; jx < R_; ++jx){
            const unsigned char* col = xh + (pb + jx)*16;
            u32x4 d0 = *(const u32x4*)(col);
            u32x4 d1 = *(const u32x4*)(col +   PW_*16);
            u32x4 d2 = *(const u32x4*)(col + 2*PW_*16);
            u32x4 d3 = *(const u32x4*)(col + 3*PW_*16);
            u32x4 d4 = *(const u32x4*)(col + 4*PW_*16);
            #pragma unroll
            for (int i = 0; i < R_; ++i, ++t){
                int tn = t + 4; if (tn > RR_-1) tn = RR_-1;
                u32x4 An = *(const u32x4*)(ug + ((size_t)tn << 10) + aoff);
                u32x4 dn = d4;
                if (i < 10) dn = *(const u32x4*)(col + (i+5)*PW_*16);
                MFMA(acc0, A0, d0);
                MFMA(acc1, A0, d2);
                A0 = A1; A1 = A2; A2 = A3; A3 = An;
                d0 = d1; d1 = d2; d2 = d3; d3 = d4; d4 = dn;
            }
        }
    }
    int ow = ox + cx;
#define EPI(ACC, F) {                                                        \
        int oh = oy + 4*wv + rb + 2*(F);                                     \
        bool valid = (oh < HO_) && (ow < WO_);                               \
        float inv = 0.f;                                                     \
        if (valid) inv = inv_xn[(size_t)b*OHW_ + oh*WO_ + ow];               \
        float* ob = out + (size_t)b*K_*OHW_ + oh*WO_ + ow;                   \
        _Pragma("unroll")                                                    \
        for (int r = 0; r < 16; ++r){                                        \
            int kp = (r & 3) + 8*(r >> 2) + 4*ks;                            \
            if (valid) ob[(size_t)kp*OHW_] = fmaxf(ACC[r], 0.f) * inv;       \
        }                                                                    \
    }
    EPI(acc0, 0); EPI(acc1, 1);
#undef EPI
}

extern "C" void kernel_launch(void* const* d_in, const int* in_sizes, int n_in,
                              void* d_out, int out_size, void* d_ws, size_t ws_size,
                              hipStream_t stream) {
    const float* x = (const float*)d_in[0];
    const float* y = (const float*)d_in[1];
    float* out = (float*)d_out;
    unsigned char* ws = (unsigned char*)d_ws;

    if (ws_size >= WS_NEED){
        unsigned char* xbf   = ws;
        unsigned char* u_g   = ws + XBF_BYTES;
        float*         s     = (float*)(ws + XBF_BYTES + UG_BYTES);
        float*         invxn = (float*)(ws + XBF_BYTES + UG_BYTES + S_BYTES);

        k_prep<<<K_ + (B_*HW_)/256, 256, 0, stream>>>(x, y, s, xbf, u_g);
        k_inv<<<(B_*OHW_)/256, 256, 0, stream>>>(s, invxn);
        k_main<<<B_*21, 256, 0, stream>>>(xbf, u_g, invxn, out);
    } else {
        unsigned char* u_g   = ws;
        float*         s     = (float*)(ws + UG_BYTES);
        float*         invxn = (float*)(ws + UG_BYTES + S_BYTES);

        k_prep_y<<<K_, 256, 0, stream>>>(y, u_g);
        k_sq<<<(B_*HW_)/256, 256, 0, stream>>>(x, s);
        k_inv<<<(B_*OHW_)/256, 256, 0, stream>>>(s, invxn);
        k_main_fb<<<B_*36, 256, LDS_FB, stream>>>(x, u_g, invxn, out);
    }
}

// Round 21
// 187.092 us; speedup vs baseline: 1.0219x; 1.0214x over previous
//
#include <hip/hip_runtime.h>
#include <hip/hip_bf16.h>

#define B_   32
#define C_   64
#define H_   96
#define W_   96
#define K_   32
#define R_   13
#define HO_  84
#define WO_  84
#define HW_  (H_*W_)      // 9216
#define OHW_ (HO_*WO_)    // 7056
#define CRR_ (C_*R_*R_)   // 10816
#define RR_  (R_*R_)      // 169

#define TILE_ 16          // fallback tile
#define PW_   28          // fallback patch width
// ---- main tile: 12 rows x 32 cols (rows exact: 84 = 7x12) ----
#define TLH_  32          // tile cols (1x32 B-frag)
#define TLV3_ 12          // tile rows (4 waves x 3 one-row frags)
#define PWW_  44          // patch width  = 32+12
#define PHH_  24          // patch height = 12+12
#define NPIX3_ (PHH_*PWW_)  // 1056
#define NEL3_  (2*NPIX3_)   // 2112 16B-elements per pass (= 33 chunks of 64)
#define HB3_   (NPIX3_*16)  // 16896 per ks-half
#define BUF3_  (2*HB3_)     // 33792: single buffer, static alloc
#define NPIX_ (PW_*PW_)   // 784 (fallback)
#define REGB_ (NPIX_*16)  // 12544 (fallback layout)
#define LDS_FB (2*REGB_)  // 25088

// ws layout (new path): xbf4 = [b][pass(4)][pix(9216)][32B]
#define XBF_BYTES  ((size_t)B_*4*HW_*32)         // 37748736
#define UG_BYTES   ((size_t)RR_*4096)            // 692224
#define S_BYTES    ((size_t)B_*HW_*4)            // 1179648
#define INV_BYTES  ((size_t)B_*OHW_*4)           // 903168
#define WS_NEED    (XBF_BYTES + UG_BYTES + S_BYTES + INV_BYTES)

typedef unsigned int u32;
typedef unsigned short u16;
typedef __attribute__((ext_vector_type(16))) float f32x16;
typedef __attribute__((ext_vector_type(4))) u32 u32x4;

static __device__ __forceinline__ u16 f2bf(float v){
    __hip_bfloat16 h = __float2bfloat16(v);  // RNE
    return *reinterpret_cast<u16*>(&h);
}

// D = A*B + D  (32x32x16 bf16)
#define MFMA(acc, a, b) asm("v_mfma_f32_32x32x16_bf16 %0, %1, %2, %0" \
                            : "+v"(acc) : "v"(a), "v"(b))

// async global->LDS DMA, 16B/lane, LDS dest = uniform base + lane*16
static __device__ __forceinline__ void gload_lds16(const void* g, void* l){
    __builtin_amdgcn_global_load_lds(
        (const __attribute__((address_space(1))) unsigned char*)g,
        (__attribute__((address_space(3))) unsigned char*)l, 16, 0, 0);
}

// ---------- device helper: y-norm + bf16 prototype tensor (one k) ----------
// u_g: [pass(4)][jx(13)][i(13)] slices of 1KB; byte = k*32 + (c&15)*2.
// A-frag: lane(kpr,ks) reads 16B at slice + kpr*32 + ks*16.
static __device__ void prep_y_block(const float* __restrict__ y,
                                    unsigned char* __restrict__ u_g,
                                    int k, int tid, float* red){
    const float* yk = y + (size_t)k * CRR_;
    float ss = 0.f;
    for (int idx = tid; idx < CRR_; idx += 256){ float v = yk[idx]; ss += v*v; }
    for (int off = 32; off; off >>= 1) ss += __shfl_down(ss, off);
    if ((tid & 63) == 0) red[tid >> 6] = ss;
    __syncthreads();
    float inv = 1.f / fmaxf(sqrtf(red[0]+red[1]+red[2]+red[3]), 1e-9f);

    int c = tid & 63, grp = tid >> 6;
    int inoff = (k << 5) | ((c & 15) << 1);
    for (int base = 0; base < RR_; base += 4){
        int ij = base + grp;
        if (ij < RR_){
            int i = ij / R_, jx = ij % R_;
            float v = yk[c*RR_ + ij] * inv;
            size_t slice = ((size_t)(c >> 4) * RR_ + jx*R_ + i) << 10;
            *(u16*)(u_g + slice + inoff) = f2bf(v);
        }
    }
}

// k1 standalone (fallback path)
__global__ void k_prep_y(const float* __restrict__ y, unsigned char* __restrict__ u_g){
    __shared__ float red[4];
    prep_y_block(y, u_g, blockIdx.x, threadIdx.x, red);
}

// ------- merged k1+k2: blocks 0..31 do y-prep; rest do sqcvt ---------------
__global__ void k_prep(const float* __restrict__ x, const float* __restrict__ y,
                       float* __restrict__ s, unsigned char* __restrict__ xbf,
                       unsigned char* __restrict__ u_g){
    __shared__ float red[4];
    int bb = blockIdx.x;
    if (bb < K_){ prep_y_block(y, u_g, bb, threadIdx.x, red); return; }
    int idx = (bb - K_)*256 + threadIdx.x;            // < 294912 exact
    int b = idx / HW_, r = idx % HW_;
    const float* xb = x + (size_t)b * C_ * HW_ + r;
    float acc = 0.f;
    #pragma unroll
    for (int q = 0; q < 4; ++q){
        int c0 = q*16;
        float a0 = xb[(size_t)(c0+0)*HW_],  a1 = xb[(size_t)(c0+1)*HW_];
        float a2 = xb[(size_t)(c0+2)*HW_],  a3 = xb[(size_t)(c0+3)*HW_];
        float a4 = xb[(size_t)(c0+4)*HW_],  a5 = xb[(size_t)(c0+5)*HW_];
        float a6 = xb[(size_t)(c0+6)*HW_],  a7 = xb[(size_t)(c0+7)*HW_];
        float a8 = xb[(size_t)(c0+8)*HW_],  a9 = xb[(size_t)(c0+9)*HW_];
        float aa = xb[(size_t)(c0+10)*HW_], ab = xb[(size_t)(c0+11)*HW_];
        float ac = xb[(size_t)(c0+12)*HW_], ad = xb[(size_t)(c0+13)*HW_];
        float ae = xb[(size_t)(c0+14)*HW_], af = xb[(size_t)(c0+15)*HW_];
        acc += a0*a0+a1*a1+a2*a2+a3*a3+a4*a4+a5*a5+a6*a6+a7*a7
             + a8*a8+a9*a9+aa*aa+ab*ab+ac*ac+ad*ad+ae*ae+af*af;
        u32x4 q0 = { f2bf(a0)|((u32)f2bf(a1)<<16), f2bf(a2)|((u32)f2bf(a3)<<16),
                     f2bf(a4)|((u32)f2bf(a5)<<16), f2bf(a6)|((u32)f2bf(a7)<<16) };
        u32x4 q1 = { f2bf(a8)|((u32)f2bf(a9)<<16), f2bf(aa)|((u32)f2bf(ab)<<16),
                     f2bf(ac)|((u32)f2bf(ad)<<16), f2bf(ae)|((u32)f2bf(af)<<16) };
        unsigned char* ob = xbf + ((size_t)(b*4 + q)*HW_ + r)*32;
        *(u32x4*)(ob)      = q0;
        *(u32x4*)(ob + 16) = q1;
    }
    s[idx] = acc;
}

// plain k2 for fallback path
__global__ void k_sq(const float* __restrict__ x, float* __restrict__ s){
    int idx = blockIdx.x*256 + threadIdx.x;
    int b = idx / HW_, r = idx % HW_;
    const float* xb = x + (size_t)b * C_ * HW_;
    float acc = 0.f;
    #pragma unroll
    for (int c = 0; c < C_; ++c){ float v = xb[(size_t)c*HW_ + r]; acc += v*v; }
    s[idx] = acc;
}

// ---------------- k3: inv_xn = 1/max(sqrt(13x13 box sum), eps) -------------
__global__ void k_inv(const float* __restrict__ s, float* __restrict__ inv_xn){
    int idx = blockIdx.x*256 + threadIdx.x;           // < 225792 exact
    int b = idx / OHW_, r = idx % OHW_;
    int oh = r / WO_, ow = r % WO_;
    const float* sb = s + (size_t)b*HW_ + oh*W_ + ow;
    float acc = 0.f;
    for (int i = 0; i < R_; ++i){
        #pragma unroll
        for (int j = 0; j < R_; ++j) acc += sb[i*W_ + j];
    }
    inv_xn[idx] = 1.f / fmaxf(sqrtf(acc), 1e-9f);
}

// ---------------- k_main: fused cosine-similarity conv ---------------------
// FINAL (revert to R17 = session best: k_main 150us, total 187.1us).
// 12x32 tile (1-row x 32-col B-frags), rows exact (84 = 7x12), 3-row rolling
// window with i<12 refill guard, A-window 4 (clamped), jx e-prefetch,
// setprio around MFMA triple, pass-major bf16 xbf, XCD-chunked swizzle,
// single 33792B static LDS buffer, DMA staging (zero ds_write).
// R19's trims (dbuf 67.6KB, unclamped A-prefetch) both regressed: residency
// is hard-capped at ~2 blocks/CU (R17/R18 proved vs LDS size, alloc kind,
// launch bounds), and at that cap the SIMD is ~88% issue-busy -> this
// structure is at its practical ceiling.
__launch_bounds__(256, 3)
__global__ void k_main(const unsigned char* __restrict__ xbf,
                       const unsigned char* __restrict__ u_g,
                       const float* __restrict__ inv_xn, float* __restrict__ out){
    __shared__ unsigned char lds[BUF3_];   // static, exact size

    int bb0 = blockIdx.x;
    int bb  = (bb0 & 7) * 84 + (bb0 >> 3);   // XCD-chunked swizzle (672 = 8*84)
    int b  = bb / 21;
    int tt = bb % 21;
    int oy = (tt / 3) * TLV3_;               // 0..72, rows exact
    int ox = (tt % 3) * TLH_;                // 0,32,64 (cols >=84 masked)

    int tid  = threadIdx.x;
    int lane = tid & 63;
    int wv   = tid >> 6;        // 0..3
    int ks   = lane >> 5;       // k-half of MFMA operands
    int nn   = lane & 31;       // B-frag col within tile / D col
    int kpr  = lane & 31;       // prototype row for A-frag

    const unsigned char* xq = xbf + (size_t)b*4*HW_*32;   // image base (pass-major)
    int aoff = (kpr << 5) + (ks << 4);      // A lane offset within 1KB slice
    int pb3  = (3*wv)*PWW_ + nn;            // frag f at tap(i,jx): pb3 + (i+f)*PWW_ + jx

    // staging: 36 padded chunks of 64 elements (16B each), 9 per wave.
    // flat element e = h*NPIX3 + p -> LDS byte e*16 (uniform base + lane*16
    // holds for ALL chunks since HB3 = NPIX3*16). Chunks 33-35 remap to 32
    // (duplicate writes of identical data: benign).
    int goff[9], loff[9];
    #pragma unroll
    for (int j = 0; j < 9; ++j){
        int cb = wv + 4*j;
        int cs = cb*64; if (cs > NEL3_-64) cs = NEL3_-64;   // 2048 cap
        int e = cs + lane;
        int h = (e >= NPIX3_);
        int p = e - (h ? NPIX3_ : 0);
        int py = p / PWW_, px = p % PWW_;
        int gy = oy + py;                             // <= 72+23 = 95: in-bounds
        int gx = ox + px; if (gx > W_-1) gx = W_-1;   // clamp feeds only invalid cols
        goff[j] = ((gy*W_ + gx) << 5) + h*16;         // pass-major pixel stride 32B
        loff[j] = cs << 4;                            // uniform chunk base
    }

#define STAGE(q) {                                                           \
        const unsigned char* src = xq + (size_t)(q)*HW_*32;                  \
        _Pragma("unroll")                                                    \
        for (int j = 0; j < 9; ++j)                                          \
            gload_lds16(src + goff[j], lds + loff[j]);                       \
    }

    f32x16 acc0 = {}, acc1 = {}, acc2 = {};
    STAGE(0);
    __syncthreads();            // vmcnt drained at barrier -> pass-0 visible

    for (int pass = 0; pass < 4; ++pass){
        const unsigned char* xh = lds + ks*HB3_;
        const unsigned char* ug = u_g + ((size_t)pass*RR_ << 10);

        u32x4 A0 = *(const u32x4*)(ug              + aoff);
        u32x4 A1 = *(const u32x4*)(ug + (1 << 10)  + aoff);
        u32x4 A2 = *(const u32x4*)(ug + (2 << 10)  + aoff);
        u32x4 A3 = *(const u32x4*)(ug + (3 << 10)  + aoff);

        // initial 3-row window for jx=0
        const unsigned char* col0 = xh + pb3*16;
        u32x4 w0 = *(const u32x4*)(col0);
        u32x4 w1 = *(const u32x4*)(col0 +   PWW_*16);
        u32x4 w2 = *(const u32x4*)(col0 + 2*PWW_*16);

        int t = 0;
        for (int jx = 0; jx < R_; ++jx){
            const unsigned char* col  = xh + (pb3 + jx)*16;
            const unsigned char* ncol = col + 16;       // next column (jx+1)
            u32x4 e0, e1, e2;
            #pragma unroll
            for (int i = 0; i < R_; ++i, ++t){
                int tn = t + 4; if (tn > RR_-1) tn = RR_-1;
                u32x4 An = *(const u32x4*)(ug + ((size_t)tn << 10) + aoff);
                u32x4 wn = w2;
                if (i < 12) wn = *(const u32x4*)(col + (i+3)*PWW_*16);
                // prefetch next-jx window rows 0..2 during tail iters
                if (i == 9)  e0 = *(const u32x4*)(ncol);
                if (i == 10) e1 = *(const u32x4*)(ncol +   PWW_*16);
                if (i == 11) e2 = *(const u32x4*)(ncol + 2*PWW_*16);
                __builtin_amdgcn_s_setprio(1);
                MFMA(acc0, A0, w0);     // frag0 (row +0): B = patch row i
                MFMA(acc1, A0, w1);     // frag1 (row +1): B = patch row i+1
                MFMA(acc2, A0, w2);     // frag2 (row +2): B = patch row i+2
                __builtin_amdgcn_s_setprio(0);
                A0 = A1; A1 = A2; A2 = A3; A3 = An;
                w0 = w1; w1 = w2; w2 = wn;
            }
            w0 = e0; w1 = e1; w2 = e2;  // last jx: dead
        }

        if (pass < 3){
            __syncthreads();    // all reads of this pass complete
            STAGE(pass+1);      // issue DMA into the (single) buffer
            __syncthreads();    // vmcnt drained -> next pass visible
        }
    }

    // ---- epilogue: relu(num) * 1/||x_win||; D: col=lane&31,
    // row = (r&3) + 8*(r>>2) + 4*(lane>>5) ----
    int ow = ox + nn;
    bool valid = (ow < WO_);    // rows always valid (84 = 7x12)
#define EPI(ACC, F) {                                                        \
        int oh = oy + 3*wv + (F);                                            \
        float inv = 0.f;                                                     \
        if (valid) inv = inv_xn[(size_t)b*OHW_ + oh*WO_ + ow];               \
        float* ob = out + (size_t)b*K_*OHW_ + oh*WO_ + ow;                   \
        _Pragma("unroll")                                                    \
        for (int r = 0; r < 16; ++r){                                        \
            int kp = (r & 3) + 8*(r >> 2) + 4*ks;                            \
            if (valid) ob[(size_t)kp*OHW_] = fmaxf(ACC[r], 0.f) * inv;       \
        }                                                                    \
    }
    EPI(acc0, 0); EPI(acc1, 1); EPI(acc2, 2);
#undef EPI
}

// ---------------- fallback k_main (R5, ds_write staging) -------------------
__launch_bounds__(256, 4)
__global__ void k_main_fb(const float* __restrict__ x, const unsigned char* __restrict__ u_g,
                          const float* __restrict__ inv_xn, float* __restrict__ out){
    extern __shared__ unsigned char lds[];
    int bb = blockIdx.x;
    int b  = bb / 36;
    int tt = bb % 36;
    int oy = (tt / 6) * TILE_;
    int ox = (tt % 6) * TILE_;
    int tid  = threadIdx.x;
    int lane = tid & 63;
    int wv   = tid >> 6;
    int ks   = lane >> 5;
    int rb   = (lane >> 4) & 1;
    int cx   = lane & 15;
    int kpr  = lane & 31;
    const float* xb = x + (size_t)b * C_ * HW_;
    int aoff = (kpr << 5) + (ks << 4);
    int pb   = (4*wv + rb) * PW_ + cx;
    f32x16 acc0 = {}, acc1 = {};
    for (int pass = 0; pass < 4; ++pass){
        if (pass) __syncthreads();
        int cbase = pass << 4;
        for (int p = tid; p < NPIX_; p += 256){
            int py = p / PW_, px = p % PW_;
            int gy = oy + py; if (gy > H_-1) gy = H_-1;
            int gx = ox + px; if (gx > W_-1) gx = W_-1;
            const float* src = xb + (size_t)cbase*HW_ + gy*W_ + gx;
            u32 w0 = f2bf(src[0*HW_])  | ((u32)f2bf(src[1*HW_])  << 16);
            u32 w1 = f2bf(src[2*HW_])  | ((u32)f2bf(src[3*HW_])  << 16);
            u32 w2 = f2bf(src[4*HW_])  | ((u32)f2bf(src[5*HW_])  << 16);
            u32 w3 = f2bf(src[6*HW_])  | ((u32)f2bf(src[7*HW_])  << 16);
            u32x4 q0 = {w0, w1, w2, w3};
            u32 v0 = f2bf(src[8*HW_])  | ((u32)f2bf(src[9*HW_])  << 16);
            u32 v1 = f2bf(src[10*HW_]) | ((u32)f2bf(src[11*HW_]) << 16);
            u32 v2 = f2bf(src[12*HW_]) | ((u32)f2bf(src[13*HW_]) << 16);
            u32 v3 = f2bf(src[14*HW_]) | ((u32)f2bf(src[15*HW_]) << 16);
            u32x4 q1 = {v0, v1, v2, v3};
            *(u32x4*)(lds +         p*16) = q0;
            *(u32x4*)(lds + REGB_ + p*16) = q1;
        }
        __syncthreads();
        const unsigned char* xh = lds + ks*REGB_;
        const unsigned char* ug = u_g + ((size_t)pass*RR_ << 10);
        u32x4 A0 = *(const u32x4*)(ug              + aoff);
        u32x4 A1 = *(const u32x4*)(ug + (1 << 10)  + aoff);
        u32x4 A2 = *(const u32x4*)(ug + (2 << 10)  + aoff);
        u32x4 A3 = *(const u32x4*)(ug + (3 << 10)  + aoff);
        int t = 0;
        for (int jx = 0; jx < R_; ++jx){
            const unsigned char* col = xh + (pb + jx)*16;
            u32x4 d0 = *(const u32x4*)(col);
            u32x4 d1 = *(const u32x4*)(col +   PW_*16);
            u32x4 d2 = *(const u32x4*)(col + 2*PW_*16);
            u32x4 d3 = *(const u32x4*)(col + 3*PW_*16);
            u32x4 d4 = *(const u32x4*)(col + 4*PW_*16);
            #pragma unroll
            for (int i = 0; i < R_; ++i, ++t){
                int tn = t + 4; if (tn > RR_-1) tn = RR_-1;
                u32x4 An = *(const u32x4*)(ug + ((size_t)tn << 10) + aoff);
                u32x4 dn = d4;
                if (i < 10) dn = *(const u32x4*)(col + (i+5)*PW_*16);
                MFMA(acc0, A0, d0);
                MFMA(acc1, A0, d2);
                A0 = A1; A1 = A2; A2 = A3; A3 = An;
                d0 = d1; d1 = d2; d2 = d3; d3 = d4; d4 = dn;
            }
        }
    }
    int ow = ox + cx;
#define EPI(ACC, F) {                                                        \
        int oh = oy + 4*wv + rb + 2*(F);                                     \
        bool valid = (oh < HO_) && (ow < WO_);                               \
        float inv = 0.f;                                                     \
        if (valid) inv = inv_xn[(size_t)b*OHW_ + oh*WO_ + ow];               \
        float* ob = out + (size_t)b*K_*OHW_ + oh*WO_ + ow;                   \
        _Pragma("unroll")                                                    \
        for (int r = 0; r < 16; ++r){                                        \
            int kp = (r & 3) + 8*(r >> 2) + 4*ks;                            \
            if (valid) ob[(size_t)kp*OHW_] = fmaxf(ACC[r], 0.f) * inv;       \
        }                                                                    \
    }
    EPI(acc0, 0); EPI(acc1, 1);
#undef EPI
}

extern "C" void kernel_launch(void* const* d_in, const int* in_sizes, int n_in,
                              void* d_out, int out_size, void* d_ws, size_t ws_size,
                              hipStream_t stream) {
    const float* x = (const float*)d_in[0];
    const float* y = (const float*)d_in[1];
    float* out = (float*)d_out;
    unsigned char* ws = (unsigned char*)d_ws;

    if (ws_size >= WS_NEED){
        unsigned char* xbf   = ws;
        unsigned char* u_g   = ws + XBF_BYTES;
        float*         s     = (float*)(ws + XBF_BYTES + UG_BYTES);
        float*         invxn = (float*)(ws + XBF_BYTES + UG_BYTES + S_BYTES);

        k_prep<<<K_ + (B_*HW_)/256, 256, 0, stream>>>(x, y, s, xbf, u_g);
        k_inv<<<(B_*OHW_)/256, 256, 0, stream>>>(s, invxn);
        k_main<<<B_*21, 256, 0, stream>>>(xbf, u_g, invxn, out);
    } else {
        unsigned char* u_g   = ws;
        float*         s     = (float*)(ws + UG_BYTES);
        float*         invxn = (float*)(ws + UG_BYTES + S_BYTES);

        k_prep_y<<<K_, 256, 0, stream>>>(y, u_g);
        k_sq<<<(B_*HW_)/256, 256, 0, stream>>>(x, s);
        k_inv<<<(B_*OHW_)/256, 256, 0, stream>>>(s, invxn);
        k_main_fb<<<B_*36, 256, LDS_FB, stream>>>(x, u_g, invxn, out);
    }
}